// Round 11
// baseline (190.186 us; speedup 1.0000x reference)
//
#include <hip/hip_runtime.h>
#include <hip/hip_bf16.h>

#define PP 256
#define BB 32
#define MM 1024
#define NN 1024

constexpr float EPSF = 1e-5f;

typedef __attribute__((ext_vector_type(8))) short short8v;
typedef __attribute__((ext_vector_type(4))) short short4v;
typedef __attribute__((ext_vector_type(4))) float f32x4;

__device__ inline float bf2f(short s) {
  union { unsigned u; float f; } cv;
  cv.u = ((unsigned)(unsigned short)s) << 16;
  return cv.f;
}
__device__ inline short f2bf(float f) {
  union { float f; unsigned u; } cv; cv.f = f;
  unsigned u = cv.u;
  unsigned r = (u + 0x7fffu + ((u >> 16) & 1u)) >> 16;
  return (short)r;
}

__device__ inline void gload16(const void* g, void* l) {
  __builtin_amdgcn_global_load_lds(
      (const __attribute__((address_space(1))) unsigned*)g,
      (__attribute__((address_space(3))) unsigned*)l, 16, 0, 0);
}

// ---------------------------------------------------------------------------
// 4 weight matrices [1024][256] f32 -> [256][1024] bf16 (transposed)
// ---------------------------------------------------------------------------
__global__ __launch_bounds__(256)
void wconv4(const float* __restrict__ s0, const float* __restrict__ s1,
            const float* __restrict__ s2, const float* __restrict__ s3,
            short* __restrict__ d0, short* __restrict__ d1,
            short* __restrict__ d2, short* __restrict__ d3)
{
  const float* src = (blockIdx.z == 0) ? s0 : (blockIdx.z == 1) ? s1
                    : (blockIdx.z == 2) ? s2 : s3;
  short* dst = (blockIdx.z == 0) ? d0 : (blockIdx.z == 1) ? d1
              : (blockIdx.z == 2) ? d2 : d3;
  __shared__ float tile[64][65];
  const int c0 = blockIdx.x * 64, r0 = blockIdx.y * 64;
  const int tid = threadIdx.x;
#pragma unroll
  for (int i = 0; i < 16; ++i) {
    int idx = i * 256 + tid;
    int r = idx >> 6, c = idx & 63;
    tile[r][c] = src[(long)(r0 + r) * 256 + (c0 + c)];
  }
  __syncthreads();
#pragma unroll
  for (int i = 0; i < 16; ++i) {
    int idx = i * 256 + tid;
    int rr = idx >> 6, cc = idx & 63;
    dst[(long)(c0 + rr) * 1024 + (r0 + cc)] = f2bf(tile[cc][rr]);
  }
}

__global__ __launch_bounds__(256)
void tr2_f32(const float* __restrict__ s0, const float* __restrict__ s1,
             float* __restrict__ d0, float* __restrict__ d1)
{
  const float* src = blockIdx.z ? s1 : s0;
  float* dst = blockIdx.z ? d1 : d0;
  __shared__ float tile[64][65];
  const int c0 = blockIdx.x * 64, r0 = blockIdx.y * 64;
  const int tid = threadIdx.x;
#pragma unroll
  for (int i = 0; i < 16; ++i) {
    int idx = i * 256 + tid;
    int r = idx >> 6, c = idx & 63;
    tile[r][c] = src[(long)(r0 + r) * 256 + (c0 + c)];
  }
  __syncthreads();
#pragma unroll
  for (int i = 0; i < 16; ++i) {
    int idx = i * 256 + tid;
    int rr = idx >> 6, cc = idx & 63;
    dst[(long)(c0 + rr) * 256 + (r0 + cc)] = tile[cc][rr];
  }
}

// ---------------------------------------------------------------------------
// Merged G1+GU.  R8 structure verbatim (best measured: 98us), scalar f2bf
// conversion (compiler-schedulable; inline-asm cvt_pk was -39%, R10):
//  - BM=128, BN=64 (grid 2048 blocks, 5 blocks/CU at 28KB LDS)
//  - triple-buffered B, depth-2 prefetch, counted vmcnt(1) barriers
//  - bijective XCD swizzle, n-fastest (x-tile L2 locality)
//  - exact f32 rowsum of x side product (nblk==0 blocks)
// ---------------------------------------------------------------------------
__global__ __launch_bounds__(256)
void gemm_xcat(const float* __restrict__ x, const short* __restrict__ wcat,
               short* __restrict__ oyyT, short* __restrict__ UT,
               float* __restrict__ rowsum)
{
  __shared__ short As[2][4096];   // [kc 0..3][m 0..127][8], XOR-swizzled, 8KB ea
  __shared__ short Bs[3][2048];   // [kc 0..3][n 0..63][8], 4KB ea

  // XCD swizzle: nwg=2048, 8 XCDs, 256 works per XCD
  const int hwid = blockIdx.x;
  const int work = (hwid & 7) * 256 + (hwid >> 3);
  const int nblk = work & 7;
  const int mblk = (work >> 3) & 7;
  const int b    = work >> 6;

  const float* Ab = x + (long)b * MM * NN;
  const int m0 = mblk * 128;
  const int n0 = nblk * 64;

  const int tid = threadIdx.x;
  const int l = tid & 63, w = tid >> 6;
  const int wr = w >> 1, wc = w & 1;
  const int lk = l >> 4, lr = l & 15;
  const int sm = tid >> 2, skc = tid & 3;

  const float* aptr0 = Ab + (long)(m0 + sm) * NN + skc * 8;
  const float* aptr1 = aptr0 + 64 * NN;
  const short* bptr = wcat + (long)(n0 + (tid & 63)) * NN + (tid >> 6) * 8;
  const int sB = tid * 8;
  const int sA0 = ((skc * 128 + sm) * 8) ^ (skc << 4);
  const int sA1 = ((skc * 128 + 64 + sm) * 8) ^ (skc << 4);

  f32x4 acc[4][2];
#pragma unroll
  for (int fm = 0; fm < 4; ++fm)
#pragma unroll
    for (int fn = 0; fn < 2; ++fn)
      acc[fm][fn] = (f32x4){0.f, 0.f, 0.f, 0.f};

  float rs0 = 0.f, rs1 = 0.f;
  const bool doRs = (nblk == 0);
  float4 a00, a01, a10, a11;

#define XC_LOAD_A(k0_) do { \
    a00 = *reinterpret_cast<const float4*>(aptr0 + (k0_)); \
    a01 = *reinterpret_cast<const float4*>(aptr0 + (k0_) + 4); \
    a10 = *reinterpret_cast<const float4*>(aptr1 + (k0_)); \
    a11 = *reinterpret_cast<const float4*>(aptr1 + (k0_) + 4); \
  } while (0)

#define XC_STAGE_B(buf_, k0_) gload16(bptr + (k0_), &Bs[buf_][sB])

#define XC_STAGE_A(buf_) do { \
    if (doRs) { \
      rs0 += a00.x + a00.y + a00.z + a00.w + a01.x + a01.y + a01.z + a01.w; \
      rs1 += a10.x + a10.y + a10.z + a10.w + a11.x + a11.y + a11.z + a11.w; \
    } \
    short8v pk0, pk1; \
    pk0[0] = f2bf(a00.x); pk0[1] = f2bf(a00.y); pk0[2] = f2bf(a00.z); pk0[3] = f2bf(a00.w); \
    pk0[4] = f2bf(a01.x); pk0[5] = f2bf(a01.y); pk0[6] = f2bf(a01.z); pk0[7] = f2bf(a01.w); \
    pk1[0] = f2bf(a10.x); pk1[1] = f2bf(a10.y); pk1[2] = f2bf(a10.z); pk1[3] = f2bf(a10.w); \
    pk1[4] = f2bf(a11.x); pk1[5] = f2bf(a11.y); pk1[6] = f2bf(a11.z); pk1[7] = f2bf(a11.w); \
    *reinterpret_cast<short8v*>(&As[buf_][sA0]) = pk0; \
    *reinterpret_cast<short8v*>(&As[buf_][sA1]) = pk1; \
  } while (0)

  // prologue: tile0 A staged; tile0+tile1 B in flight (keep tile1 flying)
  XC_LOAD_A(0);
  XC_STAGE_B(0, 0);
  XC_STAGE_B(1, 32);
  XC_STAGE_A(0);
  asm volatile("s_waitcnt vmcnt(1) lgkmcnt(0)" ::: "memory");
  __builtin_amdgcn_s_barrier();
  __builtin_amdgcn_sched_barrier(0);

  int curB = 0, nxtB = 2;
  int curA = 0;
  for (int kt = 0; kt < 32; ++kt) {
    if (kt < 31) XC_LOAD_A((kt + 1) * 32);
    if (kt < 30) XC_STAGE_B(nxtB, (kt + 2) * 32);

    short8v af[4], bf[2];
#pragma unroll
    for (int fm = 0; fm < 4; ++fm) {
      const int row = wr * 64 + fm * 16 + lr;
      af[fm] = *reinterpret_cast<const short8v*>(
          &As[curA][((lk * 128 + row) * 8) ^ (lk << 4)]);
    }
#pragma unroll
    for (int fn = 0; fn < 2; ++fn)
      bf[fn] = *reinterpret_cast<const short8v*>(
          &Bs[curB][(lk * 64 + wc * 32 + fn * 16 + lr) * 8]);
#pragma unroll
    for (int fm = 0; fm < 4; ++fm)
#pragma unroll
      for (int fn = 0; fn < 2; ++fn)
        acc[fm][fn] = __builtin_amdgcn_mfma_f32_16x16x32_bf16(
            af[fm], bf[fn], acc[fm][fn], 0, 0, 0);

    if (kt < 31) XC_STAGE_A(curA ^ 1);
    asm volatile("s_waitcnt vmcnt(1) lgkmcnt(0)" ::: "memory");
    __builtin_amdgcn_s_barrier();
    __builtin_amdgcn_sched_barrier(0);
    curA ^= 1;
    curB = (curB == 2) ? 0 : curB + 1;
    nxtB = (nxtB == 2) ? 0 : nxtB + 1;
  }

  if (doRs) {
    rs0 += __shfl_xor(rs0, 1); rs0 += __shfl_xor(rs0, 2);
    rs1 += __shfl_xor(rs1, 1); rs1 += __shfl_xor(rs1, 2);
    if (skc == 0) {
      rowsum[(long)b * MM + m0 + sm] = rs0;
      rowsum[(long)b * MM + m0 + 64 + sm] = rs1;
    }
  }

  short* Cb = ((n0 < 256) ? oyyT : UT) + (long)b * PP * MM;
  const int nb = n0 & 255;
#pragma unroll
  for (int fm = 0; fm < 4; ++fm)
#pragma unroll
    for (int fn = 0; fn < 2; ++fn) {
      const int c = nb + wc * 32 + fn * 16 + lr;
      const int rb = m0 + wr * 64 + fm * 16 + lk * 4;
      short4v pk;
#pragma unroll
      for (int j = 0; j < 4; ++j) pk[j] = f2bf(acc[fm][fn][j]);
      *reinterpret_cast<short4v*>(&Cb[(long)c * MM + rb]) = pk;
    }
}

// ---------------------------------------------------------------------------
// Row sums of bf16 oyyT [B][256][1024] (one wave per row) -> raw[b][256]
// ---------------------------------------------------------------------------
__global__ __launch_bounds__(256)
void colsum_bf16(const short* __restrict__ srcT, float* __restrict__ raw)
{
  const int b = blockIdx.y;
  const int w = threadIdx.x >> 6, l = threadIdx.x & 63;
  const int p = blockIdx.x * 4 + w;
  const short* row = srcT + ((long)b * 256 + p) * 1024;
  short8v v1 = *(const short8v*)&row[l * 8];
  short8v v2 = *(const short8v*)&row[(64 + l) * 8];
  float s = 0.f;
#pragma unroll
  for (int j = 0; j < 8; ++j) s += bf2f(v1[j]) + bf2f(v2[j]);
#pragma unroll
  for (int off = 32; off; off >>= 1) s += __shfl_down(s, off);
  if (l == 0) raw[(long)b * 256 + p] = s;
}

// rawP[b][p] = dot(wp1T[p][:], rowsum_x[b][:])
__global__ __launch_bounds__(256)
void psum_dot(const short* __restrict__ wp1T, const float* __restrict__ rowsum,
              float* __restrict__ rawP)
{
  __shared__ float rsm[1024];
  const int b = blockIdx.x;
  for (int i = threadIdx.x; i < 1024; i += 256) rsm[i] = rowsum[(long)b * 1024 + i];
  __syncthreads();
  const int p = threadIdx.x;
  const short* wrow = wp1T + (long)p * 1024;
  float s = 0.f;
  for (int k = 0; k < 1024; k += 8) {
    short8v v = *(const short8v*)&wrow[k];
#pragma unroll
    for (int j = 0; j < 8; ++j) s = fmaf(bf2f(v[j]), rsm[k + j], s);
  }
  rawP[(long)b * 256 + p] = s;
}

__device__ inline void block_reduce2(float& v1, float& v2, float* red)
{
#pragma unroll
  for (int off = 32; off > 0; off >>= 1) {
    v1 += __shfl_down(v1, off);
    v2 += __shfl_down(v2, off);
  }
  const int lane = threadIdx.x & 63, wid = threadIdx.x >> 6;
  if (lane == 0) { red[wid * 2] = v1; red[wid * 2 + 1] = v2; }
  __syncthreads();
  v1 = red[0] + red[2] + red[4] + red[6];
  v2 = red[1] + red[3] + red[5] + red[7];
}

// both sum-normalizations: blockIdx.x<32 -> o, else p
__global__ __launch_bounds__(256)
void norm_sum2(const float* __restrict__ raw2,
               const float* __restrict__ g_os, const float* __restrict__ b_os,
               const float* __restrict__ g_ps, const float* __restrict__ b_ps,
               float* __restrict__ o_sum, float* __restrict__ p_sum)
{
  const int bb = blockIdx.x;
  const bool isP = bb >= 32;
  const int b = bb & 31;
  const float* raw = raw2 + (isP ? 8192 : 0);
  const float* gamma = isP ? g_ps : g_os;
  const float* beta = isP ? b_ps : b_os;
  float* outp = isP ? p_sum : o_sum;
  const int p = threadIdx.x;
  float s = raw[(long)b * 256 + p];
  __shared__ float red[8];
  float v1 = s, v2 = s * s;
  block_reduce2(v1, v2, red);
  const float mean = v1 / 256.0f;
  float var = fmaxf((v2 - v1 * mean) / 255.0f, 0.f);
  const float inv = 1.0f / (sqrtf(var) + EPSF);
  outp[(long)b * 256 + p] = gamma[p] * (s - mean) * inv + beta[p] + 1.0f;
}

// ---------------------------------------------------------------------------
// Merged G3+G4', 64x64 tiles, K=1024, 2-phase, C^T f32 out.  Grid (4,4,64).
// ---------------------------------------------------------------------------
__global__ __launch_bounds__(256)
void gemm_dual(const short* __restrict__ oyyT, const short* __restrict__ wo2T,
               const short* __restrict__ UT, const short* __restrict__ wp1T,
               float* __restrict__ t2T, float* __restrict__ p2)
{
  constexpr int BM = 64, BN = 64;
  __shared__ short As[2][4 * BM * 8];
  __shared__ short Bs[2][4 * BN * 8];

  const int z = blockIdx.z;
  const short* Ab; const short* Bb; float* Cb;
  if (z < 32) { Ab = oyyT + (long)z * PP * MM; Bb = wo2T; Cb = t2T + ((long)z << 16); }
  else { Ab = UT + (long)(z - 32) * PP * MM; Bb = wp1T; Cb = p2 + ((long)(z - 32) << 16); }

  const int m0 = blockIdx.x * BM, n0 = blockIdx.y * BN;
  const int tid = threadIdx.x;
  const int l = tid & 63, w = tid >> 6;
  const int wr = w >> 1, wc = w & 1;
  const int lk = l >> 4, lr = l & 15;
  const int kc = tid >> 6, mloc = tid & 63;
  const short* aP = Ab + (long)(m0 + mloc) * MM + kc * 8;
  const short* bP = Bb + (long)(n0 + mloc) * MM + kc * 8;

  f32x4 acc[2][2];
#pragma unroll
  for (int fm = 0; fm < 2; ++fm)
#pragma unroll
    for (int fn = 0; fn < 2; ++fn)
      acc[fm][fn] = (f32x4){0.f, 0.f, 0.f, 0.f};

  gload16(aP, &As[0][tid * 8]);
  gload16(bP, &Bs[0][tid * 8]);
  __syncthreads();

  for (int kt = 0; kt < 32; ++kt) {
    const int cur = kt & 1, nxt = cur ^ 1;
    if (kt < 31) {
      gload16(aP + (kt + 1) * 32, &As[nxt][tid * 8]);
      gload16(bP + (kt + 1) * 32, &Bs[nxt][tid * 8]);
    }
    short8v af[2], bf[2];
#pragma unroll
    for (int fm = 0; fm < 2; ++fm)
      af[fm] = *(const short8v*)&As[cur][(lk * BM + wr * 32 + fm * 16 + lr) * 8];
#pragma unroll
    for (int fn = 0; fn < 2; ++fn)
      bf[fn] = *(const short8v*)&Bs[cur][(lk * BN + wc * 32 + fn * 16 + lr) * 8];
#pragma unroll
    for (int fm = 0; fm < 2; ++fm)
#pragma unroll
      for (int fn = 0; fn < 2; ++fn)
        acc[fm][fn] = __builtin_amdgcn_mfma_f32_16x16x32_bf16(
            af[fm], bf[fn], acc[fm][fn], 0, 0, 0);
    __syncthreads();
  }

#pragma unroll
  for (int fm = 0; fm < 2; ++fm)
#pragma unroll
    for (int fn = 0; fn < 2; ++fn) {
      const int c = n0 + wc * 32 + fn * 16 + lr;
      const int rb = m0 + wr * 32 + fm * 16 + lk * 4;
      *(f32x4*)&Cb[(long)c * PP + rb] = acc[fm][fn];
    }
}

// ---------------------------------------------------------------------------
// G5: proj = Ap @ BpT^T (row-major f32 out), 2-phase, K=256.  Grid (4,4,32).
// ---------------------------------------------------------------------------
__global__ __launch_bounds__(256)
void gemm_pp(const short* __restrict__ A, const short* __restrict__ BT,
             float* __restrict__ C)
{
  constexpr int BM = 64, BN = 64;
  __shared__ short As[2][4 * BM * 8];
  __shared__ short Bs[2][4 * BN * 8];
  const int b = blockIdx.z;
  const short* Ab = A + ((long)b << 16);
  const short* Bb = BT + ((long)b << 16);
  float* Cb = C + ((long)b << 16);
  const int m0 = blockIdx.x * BM, n0 = blockIdx.y * BN;
  const int tid = threadIdx.x;
  const int l = tid & 63, w = tid >> 6;
  const int wr = w >> 1, wc = w & 1;
  const int lk = l >> 4, lr = l & 15;
  const int kc = tid >> 6, mloc = tid & 63;
  const short* aP = Ab + (long)(m0 + mloc) * PP + kc * 8;
  const short* bP = Bb + (long)(n0 + mloc) * PP + kc * 8;

  f32x4 acc[2][2];
#pragma unroll
  for (int fm = 0; fm < 2; ++fm)
#pragma unroll
    for (int fn = 0; fn < 2; ++fn)
      acc[fm][fn] = (f32x4){0.f, 0.f, 0.f, 0.f};

  gload16(aP, &As[0][tid * 8]);
  gload16(bP, &Bs[0][tid * 8]);
  __syncthreads();

  for (int kt = 0; kt < 8; ++kt) {
    const int cur = kt & 1, nxt = cur ^ 1;
    if (kt < 7) {
      gload16(aP + (kt + 1) * 32, &As[nxt][tid * 8]);
      gload16(bP + (kt + 1) * 32, &Bs[nxt][tid * 8]);
    }
    short8v af[2], bf[2];
#pragma unroll
    for (int fm = 0; fm < 2; ++fm)
      af[fm] = *(const short8v*)&As[cur][(lk * BM + wr * 32 + fm * 16 + lr) * 8];
#pragma unroll
    for (int fn = 0; fn < 2; ++fn)
      bf[fn] = *(const short8v*)&Bs[cur][(lk * BN + wc * 32 + fn * 16 + lr) * 8];
#pragma unroll
    for (int fm = 0; fm < 2; ++fm)
#pragma unroll
      for (int fn = 0; fn < 2; ++fn)
        acc[fm][fn] = __builtin_amdgcn_mfma_f32_16x16x32_bf16(
            af[fm], bf[fn], acc[fm][fn], 0, 0, 0);
    __syncthreads();
  }

#pragma unroll
  for (int fm = 0; fm < 2; ++fm)
#pragma unroll
    for (int fn = 0; fn < 2; ++fn) {
      const int c = n0 + wc * 32 + fn * 16 + lr;
      const int rb = m0 + wr * 32 + fm * 16 + lk * 4;
#pragma unroll
      for (int j = 0; j < 4; ++j)
        Cb[(long)(rb + j) * PP + c] = acc[fm][fn][j];
    }
}

// ---------------------------------------------------------------------------
__global__ __launch_bounds__(256)
void stats_dual(const float* __restrict__ t2T, const float* __restrict__ p2,
                float* __restrict__ part)
{
  const int y = blockIdx.y, chunk = blockIdx.x;
  const float* s = (y < 32 ? t2T + ((long)y << 16)
                           : p2 + ((long)(y - 32) << 16)) + (long)chunk * 8192;
  float v1 = 0.f, v2 = 0.f;
  for (int i = threadIdx.x; i < 2048; i += 256) {
    float4 xv = *reinterpret_cast<const float4*>(&s[i * 4]);
    v1 += xv.x + xv.y + xv.z + xv.w;
    v2 = fmaf(xv.x, xv.x, fmaf(xv.y, xv.y, fmaf(xv.z, xv.z, fmaf(xv.w, xv.w, v2))));
  }
  __shared__ float red[8];
  block_reduce2(v1, v2, red);
  if (threadIdx.x == 0) {
    part[(y * 8 + chunk) * 2] = v1;
    part[(y * 8 + chunk) * 2 + 1] = v2;
  }
}

__global__ void stats_fin2(const float* __restrict__ part,
                           float* __restrict__ stO, float* __restrict__ stP)
{
  const int t = threadIdx.x;   // 64
  float v1 = 0.f, v2 = 0.f;
#pragma unroll
  for (int c = 0; c < 8; ++c) {
    v1 += part[(t * 8 + c) * 2];
    v2 += part[(t * 8 + c) * 2 + 1];
  }
  const float mean = v1 / 65536.0f;
  const float var = fmaxf((v2 - v1 * mean) / 65535.0f, 0.f);
  float* st = (t < 32) ? stO : stP;
  st[(t & 31) * 2] = mean;
  st[(t & 31) * 2 + 1] = 1.0f / (sqrtf(var) + EPSF);
}

__global__ __launch_bounds__(256)
void stats_part(const float* __restrict__ src, float* __restrict__ part)
{
  const int b = blockIdx.y, chunk = blockIdx.x;
  const float* s = src + ((long)b << 16) + (long)chunk * 8192;
  float v1 = 0.f, v2 = 0.f;
  for (int i = threadIdx.x; i < 2048; i += 256) {
    float4 xv = *reinterpret_cast<const float4*>(&s[i * 4]);
    v1 += xv.x + xv.y + xv.z + xv.w;
    v2 = fmaf(xv.x, xv.x, fmaf(xv.y, xv.y, fmaf(xv.z, xv.z, fmaf(xv.w, xv.w, v2))));
  }
  __shared__ float red[8];
  block_reduce2(v1, v2, red);
  if (threadIdx.x == 0) {
    part[(b * 8 + chunk) * 2] = v1;
    part[(b * 8 + chunk) * 2 + 1] = v2;
  }
}

__global__ void stats_fin(const float* __restrict__ part, float* __restrict__ st)
{
  const int b = threadIdx.x;
  if (b < 32) {
    float v1 = 0.f, v2 = 0.f;
#pragma unroll
    for (int c = 0; c < 8; ++c) {
      v1 += part[(b * 8 + c) * 2];
      v2 += part[(b * 8 + c) * 2 + 1];
    }
    const float mean = v1 / 65536.0f;
    const float var = fmaxf((v2 - v1 * mean) / 65535.0f, 0.f);
    st[b * 2] = mean;
    st[b * 2 + 1] = 1.0f / (sqrtf(var) + EPSF);
  }
}

__global__ __launch_bounds__(256)
void prep2(const float* __restrict__ t2T, const float* __restrict__ p2,
           const float* __restrict__ o_sum, const float* __restrict__ p_sum,
           const float* __restrict__ gamma_o, const float* __restrict__ beta_o,
           const float* __restrict__ gTp, const float* __restrict__ bTp,
           const float* __restrict__ stO, const float* __restrict__ stP,
           short* __restrict__ Ap, short* __restrict__ BpT,
           float* __restrict__ out)
{
  const long idx = (long)blockIdx.x * 256 + threadIdx.x;
  const int b = (int)(idx >> 16);
  const int rc = (int)(idx & 65535);
  const int r = rc >> 8, c = rc & 255;
  const float mO = stO[b * 2], iO = stO[b * 2 + 1];
  const float mP = stP[b * 2], iP = stP[b * 2 + 1];
  const float relA = o_sum[(b << 8) + r] * p_sum[(b << 8) + c];
  const float on = gamma_o[rc] * (t2T[idx] - mO) * iO + beta_o[rc];
  Ap[idx] = f2bf(on * relA);
  const float pn = gTp[rc] * (p2[idx] - mP) * iP + bTp[rc];
  BpT[idx] = f2bf(pn * o_sum[(b << 8) + c] * p_sum[(b << 8) + r]);
  out[(long)BB * 65536 + idx] = relA;
}

__global__ __launch_bounds__(256)
void final_half(const float* __restrict__ proj, const float* __restrict__ stF,
                const float* __restrict__ gamma, const float* __restrict__ beta,
                float* __restrict__ out)
{
  const long idx = (long)blockIdx.x * 256 + threadIdx.x;
  const int b = (int)(idx >> 16);
  const int ij = (int)(idx & 65535);
  out[idx] = gamma[ij] * (proj[idx] - stF[b * 2]) * stF[b * 2 + 1] + beta[ij];
}

extern "C" void kernel_launch(void* const* d_in, const int* in_sizes, int n_in,
                              void* d_out, int out_size, void* d_ws, size_t ws_size,
                              hipStream_t stream)
{
  const float* x    = (const float*)d_in[0];
  const float* Wo1  = (const float*)d_in[1];
  const float* Wo2  = (const float*)d_in[2];
  const float* Wp1  = (const float*)d_in[3];
  const float* Wp2  = (const float*)d_in[4];
  const float* g_os = (const float*)d_in[5];
  const float* g_o  = (const float*)d_in[6];
  const float* g_ps = (const float*)d_in[7];
  const float* g_p  = (const float*)d_in[8];
  const float* g    = (const float*)d_in[9];
  const float* b_os = (const float*)d_in[10];
  const float* b_o  = (const float*)d_in[11];
  const float* b_ps = (const float*)d_in[12];
  const float* b_p  = (const float*)d_in[13];
  const float* b_   = (const float*)d_in[14];
  float* out = (float*)d_out;

  short* wcat = (short*)d_ws;            // [512][1024] = wo1T ; wp2T
  short* wo2T = wcat + 524288;
  short* wp1T = wo2T + 262144;
  short* oyyT = wp1T + 262144;           // [B][256][1024]
  short* UT   = oyyT + 8388608;          // [B][256][1024]
  float* gTp  = (float*)(UT + 8388608);
  float* bTp  = gTp + 65536;
  float* rowsumX = bTp + 65536;          // [B][1024]
  float* t2T  = rowsumX + 32768;         // [B][256][256]
  float* p2   = t2T + 2097152;
  float* proj = p2 + 2097152;
  short* Ap   = (short*)(proj + 2097152);
  short* BpT  = Ap + 2097152;
  float* raw2 = (float*)(BpT + 2097152); // [2][32][256]
  float* o_sum = raw2 + 16384;
  float* p_sum = o_sum + 8192;
  float* part  = p_sum + 8192;           // [64][8][2]
  float* partF = part + 1024;            // [32][8][2]
  float* stO   = partF + 512;
  float* stP   = stO + 64;
  float* stF   = stP + 64;

  wconv4<<<dim3(4, 16, 4), 256, 0, stream>>>(Wo1, Wo2, Wp1, Wp2,
                                             wcat, wo2T, wp1T, wcat + 262144);
  tr2_f32<<<dim3(4, 4, 2), 256, 0, stream>>>(g_p, b_p, gTp, bTp);

  gemm_xcat<<<dim3(2048, 1, 1), 256, 0, stream>>>(x, wcat, oyyT, UT, rowsumX);

  colsum_bf16<<<dim3(64, 32), 256, 0, stream>>>(oyyT, raw2);
  psum_dot<<<32, 256, 0, stream>>>(wp1T, rowsumX, raw2 + 8192);
  norm_sum2<<<64, 256, 0, stream>>>(raw2, g_os, b_os, g_ps, b_ps, o_sum, p_sum);

  gemm_dual<<<dim3(4, 4, 64), 256, 0, stream>>>(oyyT, wo2T, UT, wp1T, t2T, p2);

  stats_dual<<<dim3(8, 64), 256, 0, stream>>>(t2T, p2, part);
  stats_fin2<<<1, 64, 0, stream>>>(part, stO, stP);

  prep2<<<8192, 256, 0, stream>>>(t2T, p2, o_sum, p_sum, g_o, b_o, gTp, bTp,
                                  stO, stP, Ap, BpT, out);

  gemm_pp<<<dim3(4, 4, 32), 256, 0, stream>>>(Ap, BpT, proj);

  stats_part<<<dim3(8, 32), 256, 0, stream>>>(proj, partF);
  stats_fin<<<1, 64, 0, stream>>>(partF, stF);

  final_half<<<8192, 256, 0, stream>>>(proj, stF, g, b_, out);
}

// Round 12
// 168.980 us; speedup vs baseline: 1.1255x; 1.1255x over previous
//
#include <hip/hip_runtime.h>
#include <hip/hip_bf16.h>

#define PP 256
#define BB 32
#define MM 1024
#define NN 1024

constexpr float EPSF = 1e-5f;

typedef __attribute__((ext_vector_type(8))) short short8v;
typedef __attribute__((ext_vector_type(4))) short short4v;
typedef __attribute__((ext_vector_type(4))) float f32x4;

__device__ inline float bf2f(short s) {
  union { unsigned u; float f; } cv;
  cv.u = ((unsigned)(unsigned short)s) << 16;
  return cv.f;
}
__device__ inline short f2bf(float f) {
  union { float f; unsigned u; } cv; cv.f = f;
  unsigned u = cv.u;
  unsigned r = (u + 0x7fffu + ((u >> 16) & 1u)) >> 16;
  return (short)r;
}

__device__ inline void gload16(const void* g, void* l) {
  __builtin_amdgcn_global_load_lds(
      (const __attribute__((address_space(1))) unsigned*)g,
      (__attribute__((address_space(3))) unsigned*)l, 16, 0, 0);
}

// ---------------------------------------------------------------------------
// 4 weight matrices [1024][256] f32 -> [256][1024] bf16 (transposed)
// ---------------------------------------------------------------------------
__global__ __launch_bounds__(256)
void wconv4(const float* __restrict__ s0, const float* __restrict__ s1,
            const float* __restrict__ s2, const float* __restrict__ s3,
            short* __restrict__ d0, short* __restrict__ d1,
            short* __restrict__ d2, short* __restrict__ d3)
{
  const float* src = (blockIdx.z == 0) ? s0 : (blockIdx.z == 1) ? s1
                    : (blockIdx.z == 2) ? s2 : s3;
  short* dst = (blockIdx.z == 0) ? d0 : (blockIdx.z == 1) ? d1
              : (blockIdx.z == 2) ? d2 : d3;
  __shared__ float tile[64][65];
  const int c0 = blockIdx.x * 64, r0 = blockIdx.y * 64;
  const int tid = threadIdx.x;
#pragma unroll
  for (int i = 0; i < 16; ++i) {
    int idx = i * 256 + tid;
    int r = idx >> 6, c = idx & 63;
    tile[r][c] = src[(long)(r0 + r) * 256 + (c0 + c)];
  }
  __syncthreads();
#pragma unroll
  for (int i = 0; i < 16; ++i) {
    int idx = i * 256 + tid;
    int rr = idx >> 6, cc = idx & 63;
    dst[(long)(c0 + rr) * 1024 + (r0 + cc)] = f2bf(tile[cc][rr]);
  }
}

__global__ __launch_bounds__(256)
void tr2_f32(const float* __restrict__ s0, const float* __restrict__ s1,
             float* __restrict__ d0, float* __restrict__ d1)
{
  const float* src = blockIdx.z ? s1 : s0;
  float* dst = blockIdx.z ? d1 : d0;
  __shared__ float tile[64][65];
  const int c0 = blockIdx.x * 64, r0 = blockIdx.y * 64;
  const int tid = threadIdx.x;
#pragma unroll
  for (int i = 0; i < 16; ++i) {
    int idx = i * 256 + tid;
    int r = idx >> 6, c = idx & 63;
    tile[r][c] = src[(long)(r0 + r) * 256 + (c0 + c)];
  }
  __syncthreads();
#pragma unroll
  for (int i = 0; i < 16; ++i) {
    int idx = i * 256 + tid;
    int rr = idx >> 6, cc = idx & 63;
    dst[(long)(c0 + rr) * 256 + (r0 + cc)] = tile[cc][rr];
  }
}

// ---------------------------------------------------------------------------
// Merged G1+GU — R5 structure verbatim (best measured COLD xcat: 104us).
// x f32 [B][1024][1024] vs wcat bf16 [512][1024].
// n0<256 -> oyyT bf16 C^T; else UT.  Rowsum of x from blockIdx.y==0.
// BM=BN=128, BK=32, double-buffered LDS, 1 barrier per K-step.
// Grid (8,4,32): y-siblings (share x-tile) differ by 8 in linear id ->
// same XCD under round-robin -> x-tile L2-resident for the 4x reuse.
// ---------------------------------------------------------------------------
__global__ __launch_bounds__(256, 4)
void gemm_xcat(const float* __restrict__ x, const short* __restrict__ wcat,
               short* __restrict__ oyyT, short* __restrict__ UT,
               float* __restrict__ rowsum)
{
  constexpr int BM = 128, BN = 128;
  __shared__ short As[2][4 * BM * 8];
  __shared__ short Bs[2][4 * BN * 8];

  const int b = blockIdx.z;
  const float* Ab = x + (long)b * MM * NN;
  const int m0 = blockIdx.x * BM;
  const int n0 = blockIdx.y * BN;

  const int tid = threadIdx.x;
  const int l = tid & 63, w = tid >> 6;
  const int wr = w >> 1, wc = w & 1;
  const int lk = l >> 4, lr = l & 15;
  const int sm = tid >> 2, skc = tid & 3;

  const float* aptr0 = Ab + (long)(m0 + sm) * NN + skc * 8;
  const float* aptr1 = Ab + (long)(m0 + 64 + sm) * NN + skc * 8;
  const int bn = tid & 127, bk0 = (tid >> 7) * 8;
  const short* bptr = wcat + (long)(n0 + bn) * NN + bk0;

  const int sA0 = ((skc * BM + sm) * 8) ^ (skc << 4);
  const int sA1 = ((skc * BM + 64 + sm) * 8) ^ (skc << 4);

  f32x4 acc[4][4];
#pragma unroll
  for (int fm = 0; fm < 4; ++fm)
#pragma unroll
    for (int fn = 0; fn < 4; ++fn)
      acc[fm][fn] = (f32x4){0.f, 0.f, 0.f, 0.f};

  float rs0 = 0.f, rs1 = 0.f;
  const bool doRs = (blockIdx.y == 0);
  float4 a00, a01, a10, a11;

#define XCAT_LOAD_A(k0_) do { \
    a00 = *reinterpret_cast<const float4*>(aptr0 + (k0_)); \
    a01 = *reinterpret_cast<const float4*>(aptr0 + (k0_) + 4); \
    a10 = *reinterpret_cast<const float4*>(aptr1 + (k0_)); \
    a11 = *reinterpret_cast<const float4*>(aptr1 + (k0_) + 4); \
  } while (0)

#define XCAT_STAGE_B(buf_, k0_) do { \
    gload16(bptr + (k0_), &Bs[buf_][tid * 8]); \
    gload16(bptr + (k0_) + 16, &Bs[buf_][(tid + 256) * 8]); \
  } while (0)

#define XCAT_STAGE_A(buf_) do { \
    if (doRs) { \
      rs0 += a00.x + a00.y + a00.z + a00.w + a01.x + a01.y + a01.z + a01.w; \
      rs1 += a10.x + a10.y + a10.z + a10.w + a11.x + a11.y + a11.z + a11.w; \
    } \
    short8v pk0, pk1; \
    pk0[0] = f2bf(a00.x); pk0[1] = f2bf(a00.y); pk0[2] = f2bf(a00.z); pk0[3] = f2bf(a00.w); \
    pk0[4] = f2bf(a01.x); pk0[5] = f2bf(a01.y); pk0[6] = f2bf(a01.z); pk0[7] = f2bf(a01.w); \
    pk1[0] = f2bf(a10.x); pk1[1] = f2bf(a10.y); pk1[2] = f2bf(a10.z); pk1[3] = f2bf(a10.w); \
    pk1[4] = f2bf(a11.x); pk1[5] = f2bf(a11.y); pk1[6] = f2bf(a11.z); pk1[7] = f2bf(a11.w); \
    *reinterpret_cast<short8v*>(&As[buf_][sA0]) = pk0; \
    *reinterpret_cast<short8v*>(&As[buf_][sA1]) = pk1; \
  } while (0)

  // prologue: tile 0
  XCAT_LOAD_A(0);
  XCAT_STAGE_B(0, 0);
  XCAT_STAGE_A(0);
  __syncthreads();

  for (int kt = 0; kt < 32; ++kt) {
    const int cur = kt & 1, nxt = cur ^ 1;
    if (kt < 31) {
      const int k1 = (kt + 1) * 32;
      XCAT_LOAD_A(k1);
      XCAT_STAGE_B(nxt, k1);
    }
    short8v af[4], bf[4];
#pragma unroll
    for (int fm = 0; fm < 4; ++fm) {
      const int row = wr * 64 + fm * 16 + lr;
      af[fm] = *reinterpret_cast<const short8v*>(&As[cur][((lk * BM + row) * 8) ^ (lk << 4)]);
    }
#pragma unroll
    for (int fn = 0; fn < 4; ++fn)
      bf[fn] = *reinterpret_cast<const short8v*>(&Bs[cur][(lk * BN + wc * 64 + fn * 16 + lr) * 8]);
#pragma unroll
    for (int fm = 0; fm < 4; ++fm)
#pragma unroll
      for (int fn = 0; fn < 4; ++fn)
        acc[fm][fn] = __builtin_amdgcn_mfma_f32_16x16x32_bf16(
            af[fm], bf[fn], acc[fm][fn], 0, 0, 0);
    if (kt < 31) XCAT_STAGE_A(nxt);
    __syncthreads();
  }

  if (doRs) {
    rs0 += __shfl_xor(rs0, 1); rs0 += __shfl_xor(rs0, 2);
    rs1 += __shfl_xor(rs1, 1); rs1 += __shfl_xor(rs1, 2);
    if ((tid & 3) == 0) {
      rowsum[(long)b * MM + m0 + sm] = rs0;
      rowsum[(long)b * MM + m0 + 64 + sm] = rs1;
    }
  }

  short* Cb = ((n0 < 256) ? oyyT : UT) + (long)b * PP * MM;
  const int nb = n0 & 255;
#pragma unroll
  for (int fm = 0; fm < 4; ++fm)
#pragma unroll
    for (int fn = 0; fn < 4; ++fn) {
      const int c = nb + wc * 64 + fn * 16 + lr;
      const int rb = m0 + wr * 64 + fm * 16 + lk * 4;
      short4v pk;
#pragma unroll
      for (int j = 0; j < 4; ++j) pk[j] = f2bf(acc[fm][fn][j]);
      *reinterpret_cast<short4v*>(&Cb[(long)c * MM + rb]) = pk;
    }
}

// ---------------------------------------------------------------------------
// Row sums of bf16 oyyT [B][256][1024] (one wave per row) -> raw[b][256]
// ---------------------------------------------------------------------------
__global__ __launch_bounds__(256)
void colsum_bf16(const short* __restrict__ srcT, float* __restrict__ raw)
{
  const int b = blockIdx.y;
  const int w = threadIdx.x >> 6, l = threadIdx.x & 63;
  const int p = blockIdx.x * 4 + w;
  const short* row = srcT + ((long)b * 256 + p) * 1024;
  short8v v1 = *(const short8v*)&row[l * 8];
  short8v v2 = *(const short8v*)&row[(64 + l) * 8];
  float s = 0.f;
#pragma unroll
  for (int j = 0; j < 8; ++j) s += bf2f(v1[j]) + bf2f(v2[j]);
#pragma unroll
  for (int off = 32; off; off >>= 1) s += __shfl_down(s, off);
  if (l == 0) raw[(long)b * 256 + p] = s;
}

// rawP[b][p] = dot(wp1T[p][:], rowsum_x[b][:])
__global__ __launch_bounds__(256)
void psum_dot(const short* __restrict__ wp1T, const float* __restrict__ rowsum,
              float* __restrict__ rawP)
{
  __shared__ float rsm[1024];
  const int b = blockIdx.x;
  for (int i = threadIdx.x; i < 1024; i += 256) rsm[i] = rowsum[(long)b * 1024 + i];
  __syncthreads();
  const int p = threadIdx.x;
  const short* wrow = wp1T + (long)p * 1024;
  float s = 0.f;
  for (int k = 0; k < 1024; k += 8) {
    short8v v = *(const short8v*)&wrow[k];
#pragma unroll
    for (int j = 0; j < 8; ++j) s = fmaf(bf2f(v[j]), rsm[k + j], s);
  }
  rawP[(long)b * 256 + p] = s;
}

__device__ inline void block_reduce2(float& v1, float& v2, float* red)
{
#pragma unroll
  for (int off = 32; off > 0; off >>= 1) {
    v1 += __shfl_down(v1, off);
    v2 += __shfl_down(v2, off);
  }
  const int lane = threadIdx.x & 63, wid = threadIdx.x >> 6;
  if (lane == 0) { red[wid * 2] = v1; red[wid * 2 + 1] = v2; }
  __syncthreads();
  v1 = red[0] + red[2] + red[4] + red[6];
  v2 = red[1] + red[3] + red[5] + red[7];
}

// both sum-normalizations: blockIdx.x<32 -> o, else p
__global__ __launch_bounds__(256)
void norm_sum2(const float* __restrict__ raw2,
               const float* __restrict__ g_os, const float* __restrict__ b_os,
               const float* __restrict__ g_ps, const float* __restrict__ b_ps,
               float* __restrict__ o_sum, float* __restrict__ p_sum)
{
  const int bb = blockIdx.x;
  const bool isP = bb >= 32;
  const int b = bb & 31;
  const float* raw = raw2 + (isP ? 8192 : 0);
  const float* gamma = isP ? g_ps : g_os;
  const float* beta = isP ? b_ps : b_os;
  float* outp = isP ? p_sum : o_sum;
  const int p = threadIdx.x;
  float s = raw[(long)b * 256 + p];
  __shared__ float red[8];
  float v1 = s, v2 = s * s;
  block_reduce2(v1, v2, red);
  const float mean = v1 / 256.0f;
  float var = fmaxf((v2 - v1 * mean) / 255.0f, 0.f);
  const float inv = 1.0f / (sqrtf(var) + EPSF);
  outp[(long)b * 256 + p] = gamma[p] * (s - mean) * inv + beta[p] + 1.0f;
}

// ---------------------------------------------------------------------------
// Merged G3+G4', 64x64 tiles, K=1024, 2-phase, C^T f32 out.  Grid (4,4,64).
// ---------------------------------------------------------------------------
__global__ __launch_bounds__(256)
void gemm_dual(const short* __restrict__ oyyT, const short* __restrict__ wo2T,
               const short* __restrict__ UT, const short* __restrict__ wp1T,
               float* __restrict__ t2T, float* __restrict__ p2)
{
  constexpr int BM = 64, BN = 64;
  __shared__ short As[2][4 * BM * 8];
  __shared__ short Bs[2][4 * BN * 8];

  const int z = blockIdx.z;
  const short* Ab; const short* Bb; float* Cb;
  if (z < 32) { Ab = oyyT + (long)z * PP * MM; Bb = wo2T; Cb = t2T + ((long)z << 16); }
  else { Ab = UT + (long)(z - 32) * PP * MM; Bb = wp1T; Cb = p2 + ((long)(z - 32) << 16); }

  const int m0 = blockIdx.x * BM, n0 = blockIdx.y * BN;
  const int tid = threadIdx.x;
  const int l = tid & 63, w = tid >> 6;
  const int wr = w >> 1, wc = w & 1;
  const int lk = l >> 4, lr = l & 15;
  const int kc = tid >> 6, mloc = tid & 63;
  const short* aP = Ab + (long)(m0 + mloc) * MM + kc * 8;
  const short* bP = Bb + (long)(n0 + mloc) * MM + kc * 8;

  f32x4 acc[2][2];
#pragma unroll
  for (int fm = 0; fm < 2; ++fm)
#pragma unroll
    for (int fn = 0; fn < 2; ++fn)
      acc[fm][fn] = (f32x4){0.f, 0.f, 0.f, 0.f};

  gload16(aP, &As[0][tid * 8]);
  gload16(bP, &Bs[0][tid * 8]);
  __syncthreads();

  for (int kt = 0; kt < 32; ++kt) {
    const int cur = kt & 1, nxt = cur ^ 1;
    if (kt < 31) {
      gload16(aP + (kt + 1) * 32, &As[nxt][tid * 8]);
      gload16(bP + (kt + 1) * 32, &Bs[nxt][tid * 8]);
    }
    short8v af[2], bf[2];
#pragma unroll
    for (int fm = 0; fm < 2; ++fm)
      af[fm] = *(const short8v*)&As[cur][(lk * BM + wr * 32 + fm * 16 + lr) * 8];
#pragma unroll
    for (int fn = 0; fn < 2; ++fn)
      bf[fn] = *(const short8v*)&Bs[cur][(lk * BN + wc * 32 + fn * 16 + lr) * 8];
#pragma unroll
    for (int fm = 0; fm < 2; ++fm)
#pragma unroll
      for (int fn = 0; fn < 2; ++fn)
        acc[fm][fn] = __builtin_amdgcn_mfma_f32_16x16x32_bf16(
            af[fm], bf[fn], acc[fm][fn], 0, 0, 0);
    __syncthreads();
  }

#pragma unroll
  for (int fm = 0; fm < 2; ++fm)
#pragma unroll
    for (int fn = 0; fn < 2; ++fn) {
      const int c = n0 + wc * 32 + fn * 16 + lr;
      const int rb = m0 + wr * 32 + fm * 16 + lk * 4;
      *(f32x4*)&Cb[(long)c * PP + rb] = acc[fm][fn];
    }
}

// ---------------------------------------------------------------------------
// G5: proj = Ap @ BpT^T (row-major f32 out), 2-phase, K=256.  Grid (4,4,32).
// ---------------------------------------------------------------------------
__global__ __launch_bounds__(256)
void gemm_pp(const short* __restrict__ A, const short* __restrict__ BT,
             float* __restrict__ C)
{
  constexpr int BM = 64, BN = 64;
  __shared__ short As[2][4 * BM * 8];
  __shared__ short Bs[2][4 * BN * 8];
  const int b = blockIdx.z;
  const short* Ab = A + ((long)b << 16);
  const short* Bb = BT + ((long)b << 16);
  float* Cb = C + ((long)b << 16);
  const int m0 = blockIdx.x * BM, n0 = blockIdx.y * BN;
  const int tid = threadIdx.x;
  const int l = tid & 63, w = tid >> 6;
  const int wr = w >> 1, wc = w & 1;
  const int lk = l >> 4, lr = l & 15;
  const int kc = tid >> 6, mloc = tid & 63;
  const short* aP = Ab + (long)(m0 + mloc) * PP + kc * 8;
  const short* bP = Bb + (long)(n0 + mloc) * PP + kc * 8;

  f32x4 acc[2][2];
#pragma unroll
  for (int fm = 0; fm < 2; ++fm)
#pragma unroll
    for (int fn = 0; fn < 2; ++fn)
      acc[fm][fn] = (f32x4){0.f, 0.f, 0.f, 0.f};

  gload16(aP, &As[0][tid * 8]);
  gload16(bP, &Bs[0][tid * 8]);
  __syncthreads();

  for (int kt = 0; kt < 8; ++kt) {
    const int cur = kt & 1, nxt = cur ^ 1;
    if (kt < 7) {
      gload16(aP + (kt + 1) * 32, &As[nxt][tid * 8]);
      gload16(bP + (kt + 1) * 32, &Bs[nxt][tid * 8]);
    }
    short8v af[2], bf[2];
#pragma unroll
    for (int fm = 0; fm < 2; ++fm)
      af[fm] = *(const short8v*)&As[cur][(lk * BM + wr * 32 + fm * 16 + lr) * 8];
#pragma unroll
    for (int fn = 0; fn < 2; ++fn)
      bf[fn] = *(const short8v*)&Bs[cur][(lk * BN + wc * 32 + fn * 16 + lr) * 8];
#pragma unroll
    for (int fm = 0; fm < 2; ++fm)
#pragma unroll
      for (int fn = 0; fn < 2; ++fn)
        acc[fm][fn] = __builtin_amdgcn_mfma_f32_16x16x32_bf16(
            af[fm], bf[fn], acc[fm][fn], 0, 0, 0);
    __syncthreads();
  }

#pragma unroll
  for (int fm = 0; fm < 2; ++fm)
#pragma unroll
    for (int fn = 0; fn < 2; ++fn) {
      const int c = n0 + wc * 32 + fn * 16 + lr;
      const int rb = m0 + wr * 32 + fm * 16 + lk * 4;
#pragma unroll
      for (int j = 0; j < 4; ++j)
        Cb[(long)(rb + j) * PP + c] = acc[fm][fn][j];
    }
}

// ---------------------------------------------------------------------------
__global__ __launch_bounds__(256)
void stats_dual(const float* __restrict__ t2T, const float* __restrict__ p2,
                float* __restrict__ part)
{
  const int y = blockIdx.y, chunk = blockIdx.x;
  const float* s = (y < 32 ? t2T + ((long)y << 16)
                           : p2 + ((long)(y - 32) << 16)) + (long)chunk * 8192;
  float v1 = 0.f, v2 = 0.f;
  for (int i = threadIdx.x; i < 2048; i += 256) {
    float4 xv = *reinterpret_cast<const float4*>(&s[i * 4]);
    v1 += xv.x + xv.y + xv.z + xv.w;
    v2 = fmaf(xv.x, xv.x, fmaf(xv.y, xv.y, fmaf(xv.z, xv.z, fmaf(xv.w, xv.w, v2))));
  }
  __shared__ float red[8];
  block_reduce2(v1, v2, red);
  if (threadIdx.x == 0) {
    part[(y * 8 + chunk) * 2] = v1;
    part[(y * 8 + chunk) * 2 + 1] = v2;
  }
}

__global__ void stats_fin2(const float* __restrict__ part,
                           float* __restrict__ stO, float* __restrict__ stP)
{
  const int t = threadIdx.x;   // 64
  float v1 = 0.f, v2 = 0.f;
#pragma unroll
  for (int c = 0; c < 8; ++c) {
    v1 += part[(t * 8 + c) * 2];
    v2 += part[(t * 8 + c) * 2 + 1];
  }
  const float mean = v1 / 65536.0f;
  const float var = fmaxf((v2 - v1 * mean) / 65535.0f, 0.f);
  float* st = (t < 32) ? stO : stP;
  st[(t & 31) * 2] = mean;
  st[(t & 31) * 2 + 1] = 1.0f / (sqrtf(var) + EPSF);
}

__global__ __launch_bounds__(256)
void stats_part(const float* __restrict__ src, float* __restrict__ part)
{
  const int b = blockIdx.y, chunk = blockIdx.x;
  const float* s = src + ((long)b << 16) + (long)chunk * 8192;
  float v1 = 0.f, v2 = 0.f;
  for (int i = threadIdx.x; i < 2048; i += 256) {
    float4 xv = *reinterpret_cast<const float4*>(&s[i * 4]);
    v1 += xv.x + xv.y + xv.z + xv.w;
    v2 = fmaf(xv.x, xv.x, fmaf(xv.y, xv.y, fmaf(xv.z, xv.z, fmaf(xv.w, xv.w, v2))));
  }
  __shared__ float red[8];
  block_reduce2(v1, v2, red);
  if (threadIdx.x == 0) {
    part[(b * 8 + chunk) * 2] = v1;
    part[(b * 8 + chunk) * 2 + 1] = v2;
  }
}

__global__ void stats_fin(const float* __restrict__ part, float* __restrict__ st)
{
  const int b = threadIdx.x;
  if (b < 32) {
    float v1 = 0.f, v2 = 0.f;
#pragma unroll
    for (int c = 0; c < 8; ++c) {
      v1 += part[(b * 8 + c) * 2];
      v2 += part[(b * 8 + c) * 2 + 1];
    }
    const float mean = v1 / 65536.0f;
    const float var = fmaxf((v2 - v1 * mean) / 65535.0f, 0.f);
    st[b * 2] = mean;
    st[b * 2 + 1] = 1.0f / (sqrtf(var) + EPSF);
  }
}

__global__ __launch_bounds__(256)
void prep2(const float* __restrict__ t2T, const float* __restrict__ p2,
           const float* __restrict__ o_sum, const float* __restrict__ p_sum,
           const float* __restrict__ gamma_o, const float* __restrict__ beta_o,
           const float* __restrict__ gTp, const float* __restrict__ bTp,
           const float* __restrict__ stO, const float* __restrict__ stP,
           short* __restrict__ Ap, short* __restrict__ BpT,
           float* __restrict__ out)
{
  const long idx = (long)blockIdx.x * 256 + threadIdx.x;
  const int b = (int)(idx >> 16);
  const int rc = (int)(idx & 65535);
  const int r = rc >> 8, c = rc & 255;
  const float mO = stO[b * 2], iO = stO[b * 2 + 1];
  const float mP = stP[b * 2], iP = stP[b * 2 + 1];
  const float relA = o_sum[(b << 8) + r] * p_sum[(b << 8) + c];
  const float on = gamma_o[rc] * (t2T[idx] - mO) * iO + beta_o[rc];
  Ap[idx] = f2bf(on * relA);
  const float pn = gTp[rc] * (p2[idx] - mP) * iP + bTp[rc];
  BpT[idx] = f2bf(pn * o_sum[(b << 8) + c] * p_sum[(b << 8) + r]);
  out[(long)BB * 65536 + idx] = relA;
}

__global__ __launch_bounds__(256)
void final_half(const float* __restrict__ proj, const float* __restrict__ stF,
                const float* __restrict__ gamma, const float* __restrict__ beta,
                float* __restrict__ out)
{
  const long idx = (long)blockIdx.x * 256 + threadIdx.x;
  const int b = (int)(idx >> 16);
  const int ij = (int)(idx & 65535);
  out[idx] = gamma[ij] * (proj[idx] - stF[b * 2]) * stF[b * 2 + 1] + beta[ij];
}

extern "C" void kernel_launch(void* const* d_in, const int* in_sizes, int n_in,
                              void* d_out, int out_size, void* d_ws, size_t ws_size,
                              hipStream_t stream)
{
  const float* x    = (const float*)d_in[0];
  const float* Wo1  = (const float*)d_in[1];
  const float* Wo2  = (const float*)d_in[2];
  const float* Wp1  = (const float*)d_in[3];
  const float* Wp2  = (const float*)d_in[4];
  const float* g_os = (const float*)d_in[5];
  const float* g_o  = (const float*)d_in[6];
  const float* g_ps = (const float*)d_in[7];
  const float* g_p  = (const float*)d_in[8];
  const float* g    = (const float*)d_in[9];
  const float* b_os = (const float*)d_in[10];
  const float* b_o  = (const float*)d_in[11];
  const float* b_ps = (const float*)d_in[12];
  const float* b_p  = (const float*)d_in[13];
  const float* b_   = (const float*)d_in[14];
  float* out = (float*)d_out;

  short* wcat = (short*)d_ws;            // [512][1024] = wo1T ; wp2T
  short* wo2T = wcat + 524288;
  short* wp1T = wo2T + 262144;
  short* oyyT = wp1T + 262144;           // [B][256][1024]
  short* UT   = oyyT + 8388608;          // [B][256][1024]
  float* gTp  = (float*)(UT + 8388608);
  float* bTp  = gTp + 65536;
  float* rowsumX = bTp + 65536;          // [B][1024]
  float* t2T  = rowsumX + 32768;         // [B][256][256]
  float* p2   = t2T + 2097152;
  float* proj = p2 + 2097152;
  short* Ap   = (short*)(proj + 2097152);
  short* BpT  = Ap + 2097152;
  float* raw2 = (float*)(BpT + 2097152); // [2][32][256]
  float* o_sum = raw2 + 16384;
  float* p_sum = o_sum + 8192;
  float* part  = p_sum + 8192;           // [64][8][2]
  float* partF = part + 1024;            // [32][8][2]
  float* stO   = partF + 512;
  float* stP   = stO + 64;
  float* stF   = stP + 64;

  wconv4<<<dim3(4, 16, 4), 256, 0, stream>>>(Wo1, Wo2, Wp1, Wp2,
                                             wcat, wo2T, wp1T, wcat + 262144);
  tr2_f32<<<dim3(4, 4, 2), 256, 0, stream>>>(g_p, b_p, gTp, bTp);

  gemm_xcat<<<dim3(8, 4, 32), 256, 0, stream>>>(x, wcat, oyyT, UT, rowsumX);

  colsum_bf16<<<dim3(64, 32), 256, 0, stream>>>(oyyT, raw2);
  psum_dot<<<32, 256, 0, stream>>>(wp1T, rowsumX, raw2 + 8192);
  norm_sum2<<<64, 256, 0, stream>>>(raw2, g_os, b_os, g_ps, b_ps, o_sum, p_sum);

  gemm_dual<<<dim3(4, 4, 64), 256, 0, stream>>>(oyyT, wo2T, UT, wp1T, t2T, p2);

  stats_dual<<<dim3(8, 64), 256, 0, stream>>>(t2T, p2, part);
  stats_fin2<<<1, 64, 0, stream>>>(part, stO, stP);

  prep2<<<8192, 256, 0, stream>>>(t2T, p2, o_sum, p_sum, g_o, b_o, gTp, bTp,
                                  stO, stP, Ap, BpT, out);

  gemm_pp<<<dim3(4, 4, 32), 256, 0, stream>>>(Ap, BpT, proj);

  stats_part<<<dim3(8, 32), 256, 0, stream>>>(proj, partF);
  stats_fin<<<1, 64, 0, stream>>>(partF, stF);

  final_half<<<8192, 256, 0, stream>>>(proj, stF, g, b_, out);
}